// Round 1
// baseline (2104.136 us; speedup 1.0000x reference)
//
#include <hip/hip_runtime.h>
#include <math.h>

#define NB 32768
#define EPS_REC 1e-4f

// Inter-stage staging (static device globals: independent of ws_size, fully
// rewritten every launch, graph-capture safe).
__device__ float g_x2[NB * 256];  // stage-1 output: B x 16 x 16
__device__ float g_x3[NB * 16];   // stage-2 output: B x 4 x 4

// Jacobi rotation (c,s) zeroing A[p][q] for 2x2 [[app,apq],[apq,aqq]],
// convention G = [[c,s],[-s,c]]: col'_p = c*colp - s*colq, col'_q = s*colp + c*colq.
// Small-angle root: t = -sgn(d)*apq/(|d|+h), d=(app-aqq)/2, h=sqrt(d^2+apq^2).
__device__ __forceinline__ void rot_cs(float app, float aqq, float apq,
                                       float& c, float& s) {
  float dd = 0.5f * (app - aqq);
  float q2 = apq * apq;
  float hh = dd * dd + q2 + 1e-30f;  // epsilon guards rsq(0); distortion only
                                     // when |d|,|apq| ~ 1e-15 (harmless)
  float h = sqrtf(hh);
  float u = fabsf(dd) + h;
  float gi = rsqrtf(u * u + q2);
  c = u * gi;
  float smag = apq * gi;
  s = (dd >= 0.f) ? -smag : smag;
}

// Two-sided Jacobi, column-per-lane. A in LDS (SA_g, col-major, stride STRIDE),
// V column in registers (v[N]), cross-lane V via shuffles.
// N even; L = N-1 rounds/sweep (circle method), M = N/2 pairs/round.
template <int N, int STRIDE>
__device__ __forceinline__ void jacobi(float* SA_g, float* CS_g, float* v,
                                       int sub, int sweeps) {
  constexpr int L = N - 1;
  constexpr int M = N / 2;
  const int base = sub * STRIDE;
  const int laneBase = (int)threadIdx.x - sub;
  for (int sw = 0; sw < sweeps; ++sw) {
    for (int r = 0; r < L; ++r) {
      // my pair: round r pairs are (L, r) and ((r+k)%L, (r-k)%L), k=1..M-1
      int kk = sub - r;
      kk += (kk < 0) ? L : 0;
      bool top = (sub == L);
      bool isP = top || (kk != 0 && kk <= M - 1);
      int partner;
      if (top) {
        partner = r;
      } else if (kk == 0) {
        partner = L;
      } else {
        partner = r + L - kk;
        if (partner >= L) partner -= L;
      }
      int pidx = top ? 0 : ((kk == 0) ? 0 : ((kk <= M - 1) ? kk : (L - kk)));
      int pp = isP ? sub : partner;
      int qq = isP ? partner : sub;
      // angle (both lanes of a pair read identical addresses -> identical c,s)
      float app = SA_g[pp * STRIDE + pp];
      float aqq = SA_g[qq * STRIDE + qq];
      float apq = SA_g[qq * STRIDE + pp];
      float c, s;
      rot_cs(app, aqq, apq, c, s);
      if (isP) {
        CS_g[pidx] = c;
        CS_g[M + pidx] = s;
      }
      __syncthreads();
      float ck[M], sk[M];
#pragma unroll
      for (int k = 0; k < M; ++k) {
        ck[k] = CS_g[k];
        sk[k] = CS_g[M + k];
      }
      float beta = isP ? -s : s;
      const int pbase = partner * STRIDE;
      int pks[M], qks[M];
      float nx[M], ny[M];
#pragma unroll
      for (int k = 0; k < M; ++k) {
        int pk, qk;
        if (k == 0) {
          pk = L;
          qk = r;
        } else {
          pk = r + k;
          if (pk >= L) pk -= L;
          qk = r - k;
          if (qk < 0) qk += L;
        }
        pks[k] = pk;
        qks[k] = qk;
        // row phase (G^T from left) on own and partner columns, then col mix
        float xo = SA_g[base + pk], yo = SA_g[base + qk];
        float xp = SA_g[pbase + pk], yp = SA_g[pbase + qk];
        float xr = ck[k] * xo - sk[k] * yo;
        float yr = sk[k] * xo + ck[k] * yo;
        float xq = ck[k] * xp - sk[k] * yp;
        float yq = sk[k] * xp + ck[k] * yp;
        nx[k] = c * xr + beta * xq;
        ny[k] = c * yr + beta * yq;
      }
      __syncthreads();
#pragma unroll
      for (int k = 0; k < M; ++k) {
        SA_g[base + pks[k]] = nx[k];
        SA_g[base + qks[k]] = ny[k];
      }
      // V columns (right-multiplication only), partner col via shuffle
      int srcLane = laneBase + partner;
#pragma unroll
      for (int i = 0; i < N; ++i) {
        float vp = __shfl(v[i], srcLane, 64);
        v[i] = c * v[i] + beta * vp;
      }
      __syncthreads();
    }
  }
}

// Stage 1: X1 = w1^T X w1 (19x19, padded to 20), ReEig via Jacobi,
// then X2 = w2^T (V Lam V^T) w2 = Y^T Lam Y with Y = V^T w2. 3 matrices/wave.
__global__ __launch_bounds__(64) void spd_stage1(const float* __restrict__ x,
                                                 const float* __restrict__ w1,
                                                 const float* __restrict__ w2) {
  __shared__ float SA[4 * 420];  // 4 groups (3 real + 1 dummy), stride 21
  __shared__ float CS[4 * 20];
  __shared__ float SL[4 * 20];
  int lane = threadIdx.x;
  int g = lane / 20;
  int sub = lane - g * 20;  // lanes 60..63 -> g=3 (dummy), sub 0..3
  int b = blockIdx.x * 3 + g;
  bool valid = (g < 3) && (b < NB);
  int bm = valid ? b : 0;
  float* SA_g = SA + g * 420;
  float* CS_g = CS + g * 20;
  float* SL_g = SL + g * 20;

  // load X column sub (X symmetric)
  float cx[19];
  const float* xb = x + bm * 361;
#pragma unroll
  for (int i = 0; i < 19; ++i) cx[i] = (sub < 19) ? xb[i * 19 + sub] : 0.f;

  // Z = w1^T X, column sub (w1 loads are lane-uniform -> scalar)
  float z[19];
#pragma unroll
  for (int i = 0; i < 19; ++i) {
    float acc = 0.f;
#pragma unroll
    for (int r = 0; r < 19; ++r) acc += w1[r * 19 + i] * cx[r];
    z[i] = acc;
  }
#pragma unroll
  for (int i = 0; i < 19; ++i) SA_g[sub * 21 + i] = z[i];
  __syncthreads();
  // X1 col sub = sum_r Z[:,r] * w1[r][sub]
  float wj[19];
#pragma unroll
  for (int r = 0; r < 19; ++r) wj[r] = (sub < 19) ? w1[r * 19 + sub] : 0.f;
  float a1[19];
#pragma unroll
  for (int i = 0; i < 19; ++i) a1[i] = 0.f;
#pragma unroll
  for (int r = 0; r < 19; ++r) {
    float wr = wj[r];
#pragma unroll
    for (int i = 0; i < 19; ++i) a1[i] += SA_g[r * 21 + i] * wr;
  }
  __syncthreads();
  // write padded A (pad col 19 = e19: exact invariant eigenvector), init V
#pragma unroll
  for (int i = 0; i < 20; ++i) {
    float av;
    if (sub < 19)
      av = (i < 19) ? a1[i] : 0.f;
    else
      av = (i == 19) ? 1.f : 0.f;
    SA_g[sub * 21 + i] = av;
  }
  float v[20];
#pragma unroll
  for (int i = 0; i < 20; ++i) v[i] = (i == sub) ? 1.f : 0.f;
  __syncthreads();

  jacobi<20, 21>(SA_g, CS_g, v, sub, 7);

  // lambda = max(diag, eps); pad eigenvalue contributes 0 (V[i<19][19]==0)
  float lam = fmaxf(SA_g[sub * 21 + sub], EPS_REC);
  SL_g[sub] = lam;
  __syncthreads();
  // overwrite SA with V columns
#pragma unroll
  for (int i = 0; i < 20; ++i) SA_g[sub * 21 + i] = v[i];
  __syncthreads();
  // Y[r][sub] = sum_i V[i][r] * w2[i][sub]  (sub<16)
  float wj2[19];
#pragma unroll
  for (int i = 0; i < 19; ++i) wj2[i] = (sub < 16) ? w2[i * 16 + sub] : 0.f;
  float y[20];
#pragma unroll
  for (int r = 0; r < 20; ++r) {
    float acc = 0.f;
#pragma unroll
    for (int i = 0; i < 19; ++i) acc += SA_g[r * 21 + i] * wj2[i];
    y[r] = acc;
  }
  __syncthreads();
  // overwrite SA with Y (slot sub holds Y[.][sub])
#pragma unroll
  for (int r = 0; r < 20; ++r) SA_g[sub * 21 + r] = y[r];
  __syncthreads();
  // X2[i][sub] = sum_r lam_r Y[r][i] Y[r][sub]
  float t[20];
#pragma unroll
  for (int r = 0; r < 20; ++r) t[r] = SL_g[r] * y[r];
  if (valid && sub < 16) {
    float* outb = g_x2 + b * 256;
#pragma unroll
    for (int i = 0; i < 16; ++i) {
      float acc = 0.f;
#pragma unroll
      for (int r = 0; r < 20; ++r) acc += SA_g[i * 21 + r] * t[r];
      outb[i * 16 + sub] = acc;
    }
  }
}

// Stage 2: ReEig(16x16) via Jacobi, then X3 = Y3^T Lam Y3, Y3 = V^T w3 (16x4).
// 4 matrices/wave, all 64 lanes active.
__global__ __launch_bounds__(64) void spd_stage2(const float* __restrict__ w3) {
  __shared__ float SA[4 * 272];  // stride 17
  __shared__ float CS[4 * 16];
  __shared__ float SL[4 * 16];
  __shared__ float YL[4 * 64];
  int lane = threadIdx.x;
  int g = lane >> 4;
  int sub = lane & 15;
  int b = blockIdx.x * 4 + g;
  float* SA_g = SA + g * 272;
  float* CS_g = CS + g * 16;
  float* SL_g = SL + g * 16;
  float* YL_g = YL + g * 64;
  const float* xb = g_x2 + b * 256;
#pragma unroll
  for (int i = 0; i < 16; ++i) SA_g[sub * 17 + i] = xb[i * 16 + sub];
  float v[16];
#pragma unroll
  for (int i = 0; i < 16; ++i) v[i] = (i == sub) ? 1.f : 0.f;
  __syncthreads();

  jacobi<16, 17>(SA_g, CS_g, v, sub, 7);

  float lam = fmaxf(SA_g[sub * 17 + sub], EPS_REC);
  SL_g[sub] = lam;
  // Y3 row sub: y3[j] = sum_i V[i][sub] * w3[i][j]
  float y3[4];
#pragma unroll
  for (int j = 0; j < 4; ++j) {
    float acc = 0.f;
#pragma unroll
    for (int i = 0; i < 16; ++i) acc += v[i] * w3[i * 4 + j];
    y3[j] = acc;
  }
#pragma unroll
  for (int j = 0; j < 4; ++j) YL_g[sub * 4 + j] = y3[j];
  __syncthreads();
  // X3[ii][jj], lane sub = ii*4+jj
  int ii = sub >> 2, jj = sub & 3;
  float acc = 0.f;
#pragma unroll
  for (int r = 0; r < 16; ++r) acc += SL_g[r] * YL_g[r * 4 + ii] * YL_g[r * 4 + jj];
  g_x3[b * 16 + sub] = acc;
}

// Stage 3: per-thread 4x4 LogEig (registers, static unrolled pairs),
// feat = V log(Lam) V^T flattened, FC(16->2), log_softmax.
__global__ __launch_bounds__(256) void spd_stage3(const float* __restrict__ fcw,
                                                  float* __restrict__ out) {
  int b = blockIdx.x * 256 + threadIdx.x;
  const float* xb = g_x3 + b * 16;
  float a[4][4];
#pragma unroll
  for (int i = 0; i < 4; ++i)
#pragma unroll
    for (int j = 0; j < 4; ++j) a[i][j] = xb[i * 4 + j];
  float vv[4][4];
#pragma unroll
  for (int i = 0; i < 4; ++i)
#pragma unroll
    for (int j = 0; j < 4; ++j) vv[i][j] = (i == j) ? 1.f : 0.f;

  constexpr int P4[6] = {0, 0, 0, 1, 1, 2};
  constexpr int Q4[6] = {1, 2, 3, 2, 3, 3};
  for (int sw = 0; sw < 6; ++sw) {
#pragma unroll
    for (int e = 0; e < 6; ++e) {
      const int p = P4[e], q = Q4[e];
      float c, s;
      rot_cs(a[p][p], a[q][q], a[p][q], c, s);
#pragma unroll
      for (int j = 0; j < 4; ++j) {
        float xx = a[p][j], yy = a[q][j];
        a[p][j] = c * xx - s * yy;
        a[q][j] = s * xx + c * yy;
      }
#pragma unroll
      for (int i = 0; i < 4; ++i) {
        float xx = a[i][p], yy = a[i][q];
        a[i][p] = c * xx - s * yy;
        a[i][q] = s * xx + c * yy;
      }
#pragma unroll
      for (int i = 0; i < 4; ++i) {
        float xx = vv[i][p], yy = vv[i][q];
        vv[i][p] = c * xx - s * yy;
        vv[i][q] = s * xx + c * yy;
      }
    }
  }
  float ll[4];
#pragma unroll
  for (int r = 0; r < 4; ++r) ll[r] = logf(fmaxf(a[r][r], 1e-12f));
  float feat[16];
#pragma unroll
  for (int i = 0; i < 4; ++i)
#pragma unroll
    for (int j = 0; j < 4; ++j) {
      float acc = 0.f;
#pragma unroll
      for (int r = 0; r < 4; ++r) acc += ll[r] * vv[i][r] * vv[j][r];
      feat[i * 4 + j] = acc;
    }
  float z0 = 0.f, z1 = 0.f;
#pragma unroll
  for (int k = 0; k < 16; ++k) {
    z0 += feat[k] * fcw[2 * k + 0];
    z1 += feat[k] * fcw[2 * k + 1];
  }
  float m = fmaxf(z0, z1);
  float lse = logf(expf(z0 - m) + expf(z1 - m));
  out[b * 2 + 0] = z0 - m - lse;
  out[b * 2 + 1] = z1 - m - lse;
#pragma unroll
  for (int k = 0; k < 16; ++k) out[2 * NB + b * 16 + k] = feat[k];
}

extern "C" void kernel_launch(void* const* d_in, const int* in_sizes, int n_in,
                              void* d_out, int out_size, void* d_ws,
                              size_t ws_size, hipStream_t stream) {
  (void)in_sizes;
  (void)n_in;
  (void)out_size;
  (void)d_ws;
  (void)ws_size;
  const float* x = (const float*)d_in[0];
  const float* w1 = (const float*)d_in[1];
  const float* w2 = (const float*)d_in[2];
  const float* w3 = (const float*)d_in[3];
  const float* fcw = (const float*)d_in[4];
  float* out = (float*)d_out;

  spd_stage1<<<(NB + 2) / 3, 64, 0, stream>>>(x, w1, w2);
  spd_stage2<<<NB / 4, 64, 0, stream>>>(w3);
  spd_stage3<<<NB / 256, 256, 0, stream>>>(fcw, out);
}

// Round 2
// 1251.846 us; speedup vs baseline: 1.6808x; 1.6808x over previous
//
#include <hip/hip_runtime.h>
#include <math.h>

#define NB 32768
#define EPS_REC 1e-4f

// Inter-stage staging (static device globals: graph-capture safe).
__device__ float g_x2[NB * 256];  // stage-1 output: B x 16 x 16
__device__ float g_x3[NB * 16];   // stage-2 output: B x 4 x 4

// Tournament (circle-method) slot permutation: content of slot s moves to
// permf(s). Slot 0 fixed; odd slots ascend, even slots descend.
// Over N-1 rounds with fixed pairing (2k,2k+1) this meets every pair once
// (verified by hand for N=4,6).
__host__ __device__ constexpr int permf(int s, int n) {
  return s == 0 ? 0
       : s == 2 ? 1
       : (s & 1) ? (s == n - 1 ? n - 2 : s + 2)
       : s - 2;
}

// Jacobi rotation (c,s) zeroing A[p][q]; G = [[c,s],[-s,c]].
__device__ __forceinline__ void rot_cs(float app, float aqq, float apq,
                                       float& c, float& s) {
  float dd = 0.5f * (app - aqq);
  float q2 = apq * apq;
  float hh = dd * dd + q2 + 1e-30f;
  float h = sqrtf(hh);
  float u = fabsf(dd) + h;
  float gi = rsqrtf(u * u + q2);
  c = u * gi;
  float smag = apq * gi;
  s = (dd >= 0.f) ? -smag : smag;
}

// Two-sided Jacobi with static slot pairing and per-round data permutation.
// A in LDS, chunk-major: SA4[t*N + j] = rows 4t..4t+3 of column-slot j.
// Lane owns column-slot sub; pairs are (2k,2k+1); after rotating, rows are
// permuted in-register and the column is written to slot permf(sub).
// U (accumulated eigenvector transform) kept as ROWS in registers:
// ur[i] = U[row sub][i]; updated with static indices, zero DS traffic.
template <int N>
__device__ __forceinline__ void jacobi_rr(float4* SA4g, float2* CSg, float* ur,
                                          int sub, int iters) {
  constexpr int M = N / 2;
  constexpr int C = N / 4;
  float* SAf = (float*)SA4g;
  const int kpair = sub >> 1;
  const bool isP = !(sub & 1);
  const int partner = sub ^ 1;
  const int pp = sub & ~1;
  const int qq = pp + 1;
  // elem(i,j) float addr = ((i>>2)*N + j)*4 + (i&3); pp even => app,apq
  // are adjacent floats in column pp (8B-aligned) -> one float2 read.
  const int appAddr = ((pp >> 2) * N + pp) * 4 + (pp & 3);
  const int aqqAddr = ((qq >> 2) * N + qq) * 4 + (qq & 3);
  const int wcol = permf(sub, N);
  for (int it = 0; it < iters; ++it) {
    float2 a01 = *(const float2*)(SAf + appAddr);  // app, apq
    float aqq = SAf[aqqAddr];
    float c, s;
    rot_cs(a01.x, aqq, a01.y, c, s);
    if (isP) CSg[kpair] = make_float2(c, s);
    __syncthreads();
    float ck[M], sk[M];
    const float4* CS4 = (const float4*)CSg;
#pragma unroll
    for (int t = 0; t < M / 2; ++t) {
      float4 q4 = CS4[t];
      ck[2 * t] = q4.x;
      sk[2 * t] = q4.y;
      ck[2 * t + 1] = q4.z;
      sk[2 * t + 1] = q4.w;
    }
    float4 oc4[C], pc4[C];
#pragma unroll
    for (int t = 0; t < C; ++t) {
      oc4[t] = SA4g[t * N + sub];
      pc4[t] = SA4g[t * N + partner];
    }
    const float* oc = (const float*)oc4;
    const float* pc = (const float*)pc4;
    float beta = isP ? -s : s;
    float nn[N], urn[N];
#pragma unroll
    for (int k2 = 0; k2 < M; ++k2) {
      const int p2 = 2 * k2, q2 = 2 * k2 + 1;
      const int dp = permf(p2, N), dq = permf(q2, N);
      float cc = ck[k2], ss = sk[k2];
      // row phase (G^T from left) on own and partner columns
      float xo = oc[p2], yo = oc[q2];
      float xp = pc[p2], yp = pc[q2];
      float xr = cc * xo - ss * yo;
      float yr = ss * xo + cc * yo;
      float xq = cc * xp - ss * yp;
      float yq = ss * xp + cc * yp;
      // column phase (own pair's rotation), rows permuted on the fly
      nn[dp] = c * xr + beta * xq;
      nn[dq] = c * yr + beta * yq;
      // U row update (columns p2,q2 mix), then permute
      float ux = ur[p2], uy = ur[q2];
      urn[dp] = cc * ux - ss * uy;
      urn[dq] = ss * ux + cc * uy;
    }
#pragma unroll
    for (int i = 0; i < N; ++i) ur[i] = urn[i];
    __syncthreads();
#pragma unroll
    for (int t = 0; t < C; ++t)
      SA4g[t * N + wcol] =
          make_float4(nn[4 * t], nn[4 * t + 1], nn[4 * t + 2], nn[4 * t + 3]);
    __syncthreads();
  }
}

// Stage 1: X1 = w1^T X w1 (19 padded to 20), ReEig via Jacobi, then
// X2 = Y^T Lam Y with Y = U^T w2. 3 matrices/wave (+1 dummy group).
__global__ __launch_bounds__(64) void spd_stage1(const float* __restrict__ x,
                                                 const float* __restrict__ w1,
                                                 const float* __restrict__ w2) {
  __shared__ float4 SA[4 * 100];  // per group: 5 chunks x 20 cols
  __shared__ float2 CS[4 * 10];
  __shared__ float SL[4 * 20];
  int lane = threadIdx.x;
  int g = lane / 20;
  int sub = lane - g * 20;  // lanes 60..63 -> g=3 dummy, sub 0..3
  int b = blockIdx.x * 3 + g;
  bool valid = (g < 3) && (b < NB);
  int bm = valid ? b : 0;
  float4* SA4g = SA + g * 100;
  float* SAf = (float*)SA4g;
  float2* CSg = CS + g * 10;
  float* SLg = SL + g * 20;

  // ---- bilinear: Z = w1^T X (col sub), then X1 = Z w1 ----
  const float* xb = x + bm * 361;
  float cx[19];
#pragma unroll
  for (int i = 0; i < 19; ++i) cx[i] = (sub < 19) ? xb[i * 19 + sub] : 0.f;
  float z[20];
  z[19] = 0.f;
#pragma unroll
  for (int i = 0; i < 19; ++i) {
    float acc = 0.f;
#pragma unroll
    for (int r = 0; r < 19; ++r) acc += w1[r * 19 + i] * cx[r];
    z[i] = acc;
  }
#pragma unroll
  for (int t = 0; t < 5; ++t)
    SA4g[t * 20 + sub] =
        make_float4(z[4 * t], z[4 * t + 1], z[4 * t + 2], z[4 * t + 3]);
  __syncthreads();
  float wj[19];
#pragma unroll
  for (int r = 0; r < 19; ++r) wj[r] = (sub < 19) ? w1[r * 19 + sub] : 0.f;
  float a1[20];
#pragma unroll
  for (int i = 0; i < 20; ++i) a1[i] = 0.f;
#pragma unroll
  for (int r = 0; r < 19; ++r) {
    float wr = wj[r];
#pragma unroll
    for (int t = 0; t < 5; ++t) {
      float4 zc = SA4g[t * 20 + r];  // Z rows 4t..4t+3, col r (broadcast)
      a1[4 * t + 0] += zc.x * wr;
      a1[4 * t + 1] += zc.y * wr;
      a1[4 * t + 2] += zc.z * wr;
      a1[4 * t + 3] += zc.w * wr;
    }
  }
  __syncthreads();
  // padded A: col 19 = 0 (diag 0 -> clamped to eps; exact invariant subspace)
#pragma unroll
  for (int t = 0; t < 5; ++t)
    SA4g[t * 20 + sub] =
        make_float4(a1[4 * t], a1[4 * t + 1], a1[4 * t + 2], a1[4 * t + 3]);
  float ur[20];
#pragma unroll
  for (int i = 0; i < 20; ++i) ur[i] = (i == sub) ? 1.f : 0.f;
  __syncthreads();

  jacobi_rr<20>(SA4g, CSg, ur, sub, 7 * 19);

  const int dAddr = ((sub >> 2) * 20 + sub) * 4 + (sub & 3);
  float lam = fmaxf(SAf[dAddr], EPS_REC);
  SLg[sub] = lam;
  __syncthreads();
  // SA col sub <- U row sub  (=> SAf elem(i,j) = U[j][i])
#pragma unroll
  for (int t = 0; t < 5; ++t)
    SA4g[t * 20 + sub] =
        make_float4(ur[4 * t], ur[4 * t + 1], ur[4 * t + 2], ur[4 * t + 3]);
  __syncthreads();
  // Y[r][sub] = sum_{i<19} U[i][r] * w2[i][sub]
  float wj2[19];
#pragma unroll
  for (int i = 0; i < 19; ++i) wj2[i] = (sub < 16) ? w2[i * 16 + sub] : 0.f;
  float y[20];
#pragma unroll
  for (int r = 0; r < 20; ++r) y[r] = 0.f;
#pragma unroll
  for (int i = 0; i < 19; ++i) {
    float wv = wj2[i];
#pragma unroll
    for (int t = 0; t < 5; ++t) {
      float4 u4 = SA4g[t * 20 + i];  // U[i][4t..4t+3] (broadcast)
      y[4 * t + 0] += u4.x * wv;
      y[4 * t + 1] += u4.y * wv;
      y[4 * t + 2] += u4.z * wv;
      y[4 * t + 3] += u4.w * wv;
    }
  }
  __syncthreads();
#pragma unroll
  for (int t = 0; t < 5; ++t)
    SA4g[t * 20 + sub] =
        make_float4(y[4 * t], y[4 * t + 1], y[4 * t + 2], y[4 * t + 3]);
  __syncthreads();
  float tr[20];
#pragma unroll
  for (int r = 0; r < 20; ++r) tr[r] = SLg[r] * y[r];
  if (valid && sub < 16) {
    float* outb = g_x2 + b * 256;
#pragma unroll
    for (int i = 0; i < 16; ++i) {
      float acc = 0.f;
#pragma unroll
      for (int t = 0; t < 5; ++t) {
        float4 yc = SA4g[t * 20 + i];  // Y rows 4t..4t+3, col i (broadcast)
        acc += yc.x * tr[4 * t] + yc.y * tr[4 * t + 1] + yc.z * tr[4 * t + 2] +
               yc.w * tr[4 * t + 3];
      }
      outb[i * 16 + sub] = acc;
    }
  }
}

// Stage 2: ReEig(16) via Jacobi, X3 = Y3^T Lam Y3 with Y3 = U^T w3 (16x4).
// 4 matrices/wave, all lanes active.
__global__ __launch_bounds__(64) void spd_stage2(const float* __restrict__ w3) {
  __shared__ float4 SA[4 * 64];  // per group: 4 chunks x 16 cols
  __shared__ float2 CS[4 * 8];
  __shared__ float SL[4 * 16];
  __shared__ float4 YL[4 * 16];
  int lane = threadIdx.x;
  int g = lane >> 4;
  int sub = lane & 15;
  int b = blockIdx.x * 4 + g;
  float4* SA4g = SA + g * 64;
  float* SAf = (float*)SA4g;
  float2* CSg = CS + g * 8;
  float* SLg = SL + g * 16;
  float* YLf = (float*)(YL + g * 16);

  const float* xb = g_x2 + b * 256;
  float ca[16];
#pragma unroll
  for (int i = 0; i < 16; ++i) ca[i] = xb[i * 16 + sub];
#pragma unroll
  for (int t = 0; t < 4; ++t)
    SA4g[t * 16 + sub] =
        make_float4(ca[4 * t], ca[4 * t + 1], ca[4 * t + 2], ca[4 * t + 3]);
  float ur[16];
#pragma unroll
  for (int i = 0; i < 16; ++i) ur[i] = (i == sub) ? 1.f : 0.f;
  __syncthreads();

  jacobi_rr<16>(SA4g, CSg, ur, sub, 7 * 15);

  const int dAddr = ((sub >> 2) * 16 + sub) * 4 + (sub & 3);
  float lam = fmaxf(SAf[dAddr], EPS_REC);
  SLg[sub] = lam;
  __syncthreads();
#pragma unroll
  for (int t = 0; t < 4; ++t)
    SA4g[t * 16 + sub] =
        make_float4(ur[4 * t], ur[4 * t + 1], ur[4 * t + 2], ur[4 * t + 3]);
  __syncthreads();
  // Y3[sub][j] = sum_i U[i][sub]*w3[i][j]; U[i][sub] = SAf elem(sub,i)
  float y3[4] = {0.f, 0.f, 0.f, 0.f};
  const int rowBase = (sub >> 2) * 64 + (sub & 3);
#pragma unroll
  for (int i = 0; i < 16; ++i) {
    float u = SAf[rowBase + i * 4];
#pragma unroll
    for (int j = 0; j < 4; ++j) y3[j] += u * w3[i * 4 + j];
  }
  ((float4*)YLf)[sub] = make_float4(y3[0], y3[1], y3[2], y3[3]);
  __syncthreads();
  int ii = sub >> 2, jj = sub & 3;
  float acc = 0.f;
#pragma unroll
  for (int r = 0; r < 16; ++r)
    acc += SLg[r] * YLf[r * 4 + ii] * YLf[r * 4 + jj];
  g_x3[b * 16 + sub] = acc;
}

// Stage 3: per-thread 4x4 LogEig in registers, FC(16->2), log_softmax.
__global__ __launch_bounds__(256) void spd_stage3(const float* __restrict__ fcw,
                                                  float* __restrict__ out) {
  int b = blockIdx.x * 256 + threadIdx.x;
  const float* xb = g_x3 + b * 16;
  float a[4][4];
#pragma unroll
  for (int i = 0; i < 4; ++i)
#pragma unroll
    for (int j = 0; j < 4; ++j) a[i][j] = xb[i * 4 + j];
  float vv[4][4];
#pragma unroll
  for (int i = 0; i < 4; ++i)
#pragma unroll
    for (int j = 0; j < 4; ++j) vv[i][j] = (i == j) ? 1.f : 0.f;

  constexpr int P4[6] = {0, 0, 0, 1, 1, 2};
  constexpr int Q4[6] = {1, 2, 3, 2, 3, 3};
  for (int sw = 0; sw < 6; ++sw) {
#pragma unroll
    for (int e = 0; e < 6; ++e) {
      const int p = P4[e], q = Q4[e];
      float c, s;
      rot_cs(a[p][p], a[q][q], a[p][q], c, s);
#pragma unroll
      for (int j = 0; j < 4; ++j) {
        float xx = a[p][j], yy = a[q][j];
        a[p][j] = c * xx - s * yy;
        a[q][j] = s * xx + c * yy;
      }
#pragma unroll
      for (int i = 0; i < 4; ++i) {
        float xx = a[i][p], yy = a[i][q];
        a[i][p] = c * xx - s * yy;
        a[i][q] = s * xx + c * yy;
      }
#pragma unroll
      for (int i = 0; i < 4; ++i) {
        float xx = vv[i][p], yy = vv[i][q];
        vv[i][p] = c * xx - s * yy;
        vv[i][q] = s * xx + c * yy;
      }
    }
  }
  float ll[4];
#pragma unroll
  for (int r = 0; r < 4; ++r) ll[r] = logf(fmaxf(a[r][r], 1e-12f));
  float feat[16];
#pragma unroll
  for (int i = 0; i < 4; ++i)
#pragma unroll
    for (int j = 0; j < 4; ++j) {
      float acc = 0.f;
#pragma unroll
      for (int r = 0; r < 4; ++r) acc += ll[r] * vv[i][r] * vv[j][r];
      feat[i * 4 + j] = acc;
    }
  float z0 = 0.f, z1 = 0.f;
#pragma unroll
  for (int k = 0; k < 16; ++k) {
    z0 += feat[k] * fcw[2 * k + 0];
    z1 += feat[k] * fcw[2 * k + 1];
  }
  float m = fmaxf(z0, z1);
  float lse = logf(expf(z0 - m) + expf(z1 - m));
  out[b * 2 + 0] = z0 - m - lse;
  out[b * 2 + 1] = z1 - m - lse;
#pragma unroll
  for (int k = 0; k < 16; ++k) out[2 * NB + b * 16 + k] = feat[k];
}

extern "C" void kernel_launch(void* const* d_in, const int* in_sizes, int n_in,
                              void* d_out, int out_size, void* d_ws,
                              size_t ws_size, hipStream_t stream) {
  (void)in_sizes;
  (void)n_in;
  (void)out_size;
  (void)d_ws;
  (void)ws_size;
  const float* x = (const float*)d_in[0];
  const float* w1 = (const float*)d_in[1];
  const float* w2 = (const float*)d_in[2];
  const float* w3 = (const float*)d_in[3];
  const float* fcw = (const float*)d_in[4];
  float* out = (float*)d_out;

  spd_stage1<<<(NB + 2) / 3, 64, 0, stream>>>(x, w1, w2);
  spd_stage2<<<NB / 4, 64, 0, stream>>>(w3);
  spd_stage3<<<NB / 256, 256, 0, stream>>>(fcw, out);
}

// Round 3
// 928.421 us; speedup vs baseline: 2.2664x; 1.3484x over previous
//
#include <hip/hip_runtime.h>
#include <math.h>

#define NB 32768
#define EPS_REC 1e-4f

// Inter-stage staging (static device globals: graph-capture safe).
__device__ float g_x2[NB * 256];  // stage-1 output: B x 16 x 16
__device__ float g_x3[NB * 16];   // stage-2 output: B x 4 x 4

// Wave-synchronous "barrier": matrix groups live entirely inside one wave64,
// lanes run in lockstep, and same-wave LDS ops complete in order in the DS
// pipe. Only compiler reordering must be inhibited -> zero HW cost.
__device__ __forceinline__ void wsync() {
  asm volatile("" ::: "memory");
  __builtin_amdgcn_wave_barrier();
  asm volatile("" ::: "memory");
}

// Tournament (circle-method) slot permutation: content of slot s moves to
// permf(s). Slot 0 fixed; odd slots ascend, even slots descend. Over N-1
// rounds with fixed pairing (2k,2k+1) every pair meets exactly once.
__host__ __device__ constexpr int permf(int s, int n) {
  return s == 0 ? 0
       : s == 2 ? 1
       : (s & 1) ? (s == n - 1 ? n - 2 : s + 2)
       : s - 2;
}

// Jacobi rotation (c,s) zeroing A[p][q]; G = [[c,s],[-s,c]].
__device__ __forceinline__ void rot_cs(float app, float aqq, float apq,
                                       float& c, float& s) {
  float dd = 0.5f * (app - aqq);
  float q2 = apq * apq;
  float hh = dd * dd + q2 + 1e-30f;
  float h = sqrtf(hh);
  float u = fabsf(dd) + h;
  float gi = rsqrtf(u * u + q2);
  c = u * gi;
  float smag = apq * gi;
  s = (dd >= 0.f) ? -smag : smag;
}

// Two-sided Jacobi with static slot pairing and per-round data permutation.
// A in LDS, chunk-major: SA4[t*N + j] = rows 4t..4t+3 of column-slot j.
// Lane owns column-slot sub; pairs are (2k,2k+1); after rotating, rows are
// permuted in-register and the column is written to slot permf(sub).
// U kept as ROWS in registers (ur[i] = U[row sub][i]): zero DS traffic.
// Wave-synchronous: no s_barrier anywhere.
template <int N>
__device__ __forceinline__ void jacobi_rr(float4* SA4g, float2* CSg, float* ur,
                                          int sub, int iters) {
  constexpr int M = N / 2;
  constexpr int C = N / 4;
  float* SAf = (float*)SA4g;
  const int kpair = sub >> 1;
  const bool isP = !(sub & 1);
  const int partner = sub ^ 1;
  const int pp = sub & ~1;
  const int qq = pp + 1;
  const int appAddr = ((pp >> 2) * N + pp) * 4 + (pp & 3);
  const int aqqAddr = ((qq >> 2) * N + qq) * 4 + (qq & 3);
  const int wcol = permf(sub, N);
#pragma unroll 1
  for (int it = 0; it < iters; ++it) {
    float2 a01 = *(const float2*)(SAf + appAddr);  // app, apq
    float aqq = SAf[aqqAddr];
    float c, s;
    rot_cs(a01.x, aqq, a01.y, c, s);
    if (isP) CSg[kpair] = make_float2(c, s);
    wsync();
    float ck[M], sk[M];
    const float4* CS4 = (const float4*)CSg;
#pragma unroll
    for (int t = 0; t < M / 2; ++t) {
      float4 q4 = CS4[t];
      ck[2 * t] = q4.x;
      sk[2 * t] = q4.y;
      ck[2 * t + 1] = q4.z;
      sk[2 * t + 1] = q4.w;
    }
    float4 oc4[C], pc4[C];
#pragma unroll
    for (int t = 0; t < C; ++t) {
      oc4[t] = SA4g[t * N + sub];
      pc4[t] = SA4g[t * N + partner];
    }
    const float* oc = (const float*)oc4;
    const float* pc = (const float*)pc4;
    float beta = isP ? -s : s;
    float nn[N], urn[N];
#pragma unroll
    for (int k2 = 0; k2 < M; ++k2) {
      const int p2 = 2 * k2, q2 = 2 * k2 + 1;
      const int dp = permf(p2, N), dq = permf(q2, N);
      float cc = ck[k2], ss = sk[k2];
      float xo = oc[p2], yo = oc[q2];
      float xp = pc[p2], yp = pc[q2];
      float xr = cc * xo - ss * yo;
      float yr = ss * xo + cc * yo;
      float xq = cc * xp - ss * yp;
      float yq = ss * xp + cc * yp;
      nn[dp] = c * xr + beta * xq;
      nn[dq] = c * yr + beta * yq;
      float ux = ur[p2], uy = ur[q2];
      urn[dp] = cc * ux - ss * uy;
      urn[dq] = ss * ux + cc * uy;
    }
#pragma unroll
    for (int i = 0; i < N; ++i) ur[i] = urn[i];
    wsync();  // all reads of old columns precede any overwrite (program order)
#pragma unroll
    for (int t = 0; t < C; ++t)
      SA4g[t * N + wcol] =
          make_float4(nn[4 * t], nn[4 * t + 1], nn[4 * t + 2], nn[4 * t + 3]);
    wsync();
  }
}

// Stage 1: X1 = w1^T X w1 (19 padded to 20), ReEig via Jacobi, then
// X2 = Y^T Lam Y with Y = U^T w2. 3 matrices per wave (lanes 60..63 idle ->
// shared dummy slot 6), 128-thread blocks = 6 matrices.
__global__ __launch_bounds__(128) void spd_stage1(const float* __restrict__ x,
                                                  const float* __restrict__ w1,
                                                  const float* __restrict__ w2) {
  __shared__ float4 SA[7 * 100];  // 6 real groups + 1 dummy, 5 chunks x 20
  __shared__ float2 CS[7 * 10];
  __shared__ float SL[7 * 20];
  int tid = threadIdx.x;
  int wid = tid >> 6;
  int lane = tid & 63;
  int gl = lane / 20;           // 0..3 (3 = idle lanes 60..63)
  int sub = lane - gl * 20;
  bool lane_ok = (gl < 3);
  int g = lane_ok ? (wid * 3 + gl) : 6;
  int b = blockIdx.x * 6 + g;
  bool valid = lane_ok && (b < NB);
  int bm = valid ? b : 0;
  float4* SA4g = SA + g * 100;
  float* SAf = (float*)SA4g;
  float2* CSg = CS + g * 10;
  float* SLg = SL + g * 20;

  // ---- bilinear: Z = w1^T X (col sub), then X1 = Z w1 ----
  const float* xb = x + bm * 361;
  float cx[19];
#pragma unroll
  for (int i = 0; i < 19; ++i) cx[i] = (sub < 19) ? xb[i * 19 + sub] : 0.f;
  float z[20];
  z[19] = 0.f;
#pragma unroll
  for (int i = 0; i < 19; ++i) {
    float acc = 0.f;
#pragma unroll
    for (int r = 0; r < 19; ++r) acc += w1[r * 19 + i] * cx[r];
    z[i] = acc;
  }
#pragma unroll
  for (int t = 0; t < 5; ++t)
    SA4g[t * 20 + sub] =
        make_float4(z[4 * t], z[4 * t + 1], z[4 * t + 2], z[4 * t + 3]);
  wsync();
  float wj[19];
#pragma unroll
  for (int r = 0; r < 19; ++r) wj[r] = (sub < 19) ? w1[r * 19 + sub] : 0.f;
  float a1[20];
#pragma unroll
  for (int i = 0; i < 20; ++i) a1[i] = 0.f;
#pragma unroll
  for (int r = 0; r < 19; ++r) {
    float wr = wj[r];
#pragma unroll
    for (int t = 0; t < 5; ++t) {
      float4 zc = SA4g[t * 20 + r];  // Z rows 4t..4t+3, col r (broadcast)
      a1[4 * t + 0] += zc.x * wr;
      a1[4 * t + 1] += zc.y * wr;
      a1[4 * t + 2] += zc.z * wr;
      a1[4 * t + 3] += zc.w * wr;
    }
  }
  wsync();
  // padded A: col 19 = 0 (diag 0 -> clamped to eps; exact invariant subspace)
#pragma unroll
  for (int t = 0; t < 5; ++t)
    SA4g[t * 20 + sub] =
        make_float4(a1[4 * t], a1[4 * t + 1], a1[4 * t + 2], a1[4 * t + 3]);
  float ur[20];
#pragma unroll
  for (int i = 0; i < 20; ++i) ur[i] = (i == sub) ? 1.f : 0.f;
  wsync();

  jacobi_rr<20>(SA4g, CSg, ur, sub, 5 * 19);

  const int dAddr = ((sub >> 2) * 20 + sub) * 4 + (sub & 3);
  float lam = fmaxf(SAf[dAddr], EPS_REC);
  SLg[sub] = lam;
  wsync();
  // SA col sub <- U row sub  (=> SAf elem(i,j) = U[j][i])
#pragma unroll
  for (int t = 0; t < 5; ++t)
    SA4g[t * 20 + sub] =
        make_float4(ur[4 * t], ur[4 * t + 1], ur[4 * t + 2], ur[4 * t + 3]);
  wsync();
  // Y[r][sub] = sum_{i<19} U[i][r] * w2[i][sub]
  float wj2[19];
#pragma unroll
  for (int i = 0; i < 19; ++i) wj2[i] = (sub < 16) ? w2[i * 16 + sub] : 0.f;
  float y[20];
#pragma unroll
  for (int r = 0; r < 20; ++r) y[r] = 0.f;
#pragma unroll
  for (int i = 0; i < 19; ++i) {
    float wv = wj2[i];
#pragma unroll
    for (int t = 0; t < 5; ++t) {
      float4 u4 = SA4g[t * 20 + i];  // U[i][4t..4t+3] (broadcast)
      y[4 * t + 0] += u4.x * wv;
      y[4 * t + 1] += u4.y * wv;
      y[4 * t + 2] += u4.z * wv;
      y[4 * t + 3] += u4.w * wv;
    }
  }
  wsync();
#pragma unroll
  for (int t = 0; t < 5; ++t)
    SA4g[t * 20 + sub] =
        make_float4(y[4 * t], y[4 * t + 1], y[4 * t + 2], y[4 * t + 3]);
  wsync();
  float tr[20];
#pragma unroll
  for (int r = 0; r < 20; ++r) tr[r] = SLg[r] * y[r];
  if (valid && sub < 16) {
    float* outb = g_x2 + b * 256;
#pragma unroll
    for (int i = 0; i < 16; ++i) {
      float acc = 0.f;
#pragma unroll
      for (int t = 0; t < 5; ++t) {
        float4 yc = SA4g[t * 20 + i];  // Y rows 4t..4t+3, col i (broadcast)
        acc += yc.x * tr[4 * t] + yc.y * tr[4 * t + 1] + yc.z * tr[4 * t + 2] +
               yc.w * tr[4 * t + 3];
      }
      outb[i * 16 + sub] = acc;
    }
  }
}

// Stage 2: ReEig(16) via Jacobi, X3 = Y3^T Lam Y3 with Y3 = U^T w3 (16x4).
// 4 matrices per wave, 128-thread blocks = 8 matrices, all lanes active.
__global__ __launch_bounds__(128) void spd_stage2(const float* __restrict__ w3) {
  __shared__ float4 SA[8 * 64];
  __shared__ float2 CS[8 * 8];
  __shared__ float SL[8 * 16];
  __shared__ float4 YL[8 * 16];
  int tid = threadIdx.x;
  int wid = tid >> 6;
  int lane = tid & 63;
  int gl = lane >> 4;
  int sub = lane & 15;
  int g = wid * 4 + gl;
  int b = blockIdx.x * 8 + g;
  float4* SA4g = SA + g * 64;
  float* SAf = (float*)SA4g;
  float2* CSg = CS + g * 8;
  float* SLg = SL + g * 16;
  float* YLf = (float*)(YL + g * 16);

  const float* xb = g_x2 + b * 256;
  float ca[16];
#pragma unroll
  for (int i = 0; i < 16; ++i) ca[i] = xb[i * 16 + sub];
#pragma unroll
  for (int t = 0; t < 4; ++t)
    SA4g[t * 16 + sub] =
        make_float4(ca[4 * t], ca[4 * t + 1], ca[4 * t + 2], ca[4 * t + 3]);
  float ur[16];
#pragma unroll
  for (int i = 0; i < 16; ++i) ur[i] = (i == sub) ? 1.f : 0.f;
  wsync();

  jacobi_rr<16>(SA4g, CSg, ur, sub, 5 * 15);

  const int dAddr = ((sub >> 2) * 16 + sub) * 4 + (sub & 3);
  float lam = fmaxf(SAf[dAddr], EPS_REC);
  SLg[sub] = lam;
  wsync();
#pragma unroll
  for (int t = 0; t < 4; ++t)
    SA4g[t * 16 + sub] =
        make_float4(ur[4 * t], ur[4 * t + 1], ur[4 * t + 2], ur[4 * t + 3]);
  wsync();
  // Y3[sub][j] = sum_i U[i][sub]*w3[i][j]; U[i][sub] = SAf elem(sub,i)
  float y3[4] = {0.f, 0.f, 0.f, 0.f};
  const int rowBase = (sub >> 2) * 64 + (sub & 3);
#pragma unroll
  for (int i = 0; i < 16; ++i) {
    float u = SAf[rowBase + i * 4];
#pragma unroll
    for (int j = 0; j < 4; ++j) y3[j] += u * w3[i * 4 + j];
  }
  ((float4*)YLf)[sub] = make_float4(y3[0], y3[1], y3[2], y3[3]);
  wsync();
  int ii = sub >> 2, jj = sub & 3;
  float acc = 0.f;
#pragma unroll
  for (int r = 0; r < 16; ++r)
    acc += SLg[r] * YLf[r * 4 + ii] * YLf[r * 4 + jj];
  g_x3[b * 16 + sub] = acc;
}

// Stage 3: per-thread 4x4 LogEig in registers, FC(16->2), log_softmax.
__global__ __launch_bounds__(256) void spd_stage3(const float* __restrict__ fcw,
                                                  float* __restrict__ out) {
  int b = blockIdx.x * 256 + threadIdx.x;
  const float* xb = g_x3 + b * 16;
  float a[4][4];
#pragma unroll
  for (int i = 0; i < 4; ++i)
#pragma unroll
    for (int j = 0; j < 4; ++j) a[i][j] = xb[i * 4 + j];
  float vv[4][4];
#pragma unroll
  for (int i = 0; i < 4; ++i)
#pragma unroll
    for (int j = 0; j < 4; ++j) vv[i][j] = (i == j) ? 1.f : 0.f;

  constexpr int P4[6] = {0, 0, 0, 1, 1, 2};
  constexpr int Q4[6] = {1, 2, 3, 2, 3, 3};
  for (int sw = 0; sw < 6; ++sw) {
#pragma unroll
    for (int e = 0; e < 6; ++e) {
      const int p = P4[e], q = Q4[e];
      float c, s;
      rot_cs(a[p][p], a[q][q], a[p][q], c, s);
#pragma unroll
      for (int j = 0; j < 4; ++j) {
        float xx = a[p][j], yy = a[q][j];
        a[p][j] = c * xx - s * yy;
        a[q][j] = s * xx + c * yy;
      }
#pragma unroll
      for (int i = 0; i < 4; ++i) {
        float xx = a[i][p], yy = a[i][q];
        a[i][p] = c * xx - s * yy;
        a[i][q] = s * xx + c * yy;
      }
#pragma unroll
      for (int i = 0; i < 4; ++i) {
        float xx = vv[i][p], yy = vv[i][q];
        vv[i][p] = c * xx - s * yy;
        vv[i][q] = s * xx + c * yy;
      }
    }
  }
  float ll[4];
#pragma unroll
  for (int r = 0; r < 4; ++r) ll[r] = logf(fmaxf(a[r][r], 1e-12f));
  float feat[16];
#pragma unroll
  for (int i = 0; i < 4; ++i)
#pragma unroll
    for (int j = 0; j < 4; ++j) {
      float acc = 0.f;
#pragma unroll
      for (int r = 0; r < 4; ++r) acc += ll[r] * vv[i][r] * vv[j][r];
      feat[i * 4 + j] = acc;
    }
  float z0 = 0.f, z1 = 0.f;
#pragma unroll
  for (int k = 0; k < 16; ++k) {
    z0 += feat[k] * fcw[2 * k + 0];
    z1 += feat[k] * fcw[2 * k + 1];
  }
  float m = fmaxf(z0, z1);
  float lse = logf(expf(z0 - m) + expf(z1 - m));
  out[b * 2 + 0] = z0 - m - lse;
  out[b * 2 + 1] = z1 - m - lse;
#pragma unroll
  for (int k = 0; k < 16; ++k) out[2 * NB + b * 16 + k] = feat[k];
}

extern "C" void kernel_launch(void* const* d_in, const int* in_sizes, int n_in,
                              void* d_out, int out_size, void* d_ws,
                              size_t ws_size, hipStream_t stream) {
  (void)in_sizes;
  (void)n_in;
  (void)out_size;
  (void)d_ws;
  (void)ws_size;
  const float* x = (const float*)d_in[0];
  const float* w1 = (const float*)d_in[1];
  const float* w2 = (const float*)d_in[2];
  const float* w3 = (const float*)d_in[3];
  const float* fcw = (const float*)d_in[4];
  float* out = (float*)d_out;

  spd_stage1<<<(NB + 5) / 6, 128, 0, stream>>>(x, w1, w2);
  spd_stage2<<<NB / 8, 128, 0, stream>>>(w3);
  spd_stage3<<<NB / 256, 256, 0, stream>>>(fcw, out);
}

// Round 4
// 769.271 us; speedup vs baseline: 2.7352x; 1.2069x over previous
//
#include <hip/hip_runtime.h>
#include <math.h>

#define NB 32768
#define EPS_REC 1e-4f

// Inter-stage staging (static device globals: graph-capture safe).
__device__ float g_x2[NB * 256];  // stage-1 output: B x 16 x 16
__device__ float g_x3[NB * 16];   // stage-2 output: B x 4 x 4

// Wave-synchronous "barrier": matrix groups live entirely inside one wave64,
// lanes run in lockstep, same-wave LDS ops complete in order. Only compiler
// reordering must be inhibited -> zero HW cost.
__device__ __forceinline__ void wsync() {
  asm volatile("" ::: "memory");
  __builtin_amdgcn_wave_barrier();
  asm volatile("" ::: "memory");
}

// Swap values between adjacent lanes (lane ^ 1) via DPP quad_perm [1,0,3,2]
// (0xB1). Pairs (2k,2k+1) are even-aligned so they never cross a quad.
// VALU-pipe op: no DS traffic.
__device__ __forceinline__ float dpp_swap1(float x) {
  int xi = __builtin_bit_cast(int, x);
  int yi = __builtin_amdgcn_update_dpp(xi, xi, 0xB1, 0xF, 0xF, true);
  return __builtin_bit_cast(float, yi);
}

// Tournament (circle-method) slot permutation: content of slot s moves to
// permf(s). Over N-1 rounds with fixed pairing (2k,2k+1) every pair meets
// exactly once.
__host__ __device__ constexpr int permf(int s, int n) {
  return s == 0 ? 0
       : s == 2 ? 1
       : (s & 1) ? (s == n - 1 ? n - 2 : s + 2)
       : s - 2;
}

// Jacobi rotation (c,s) zeroing A[p][q]; G = [[c,s],[-s,c]].
__device__ __forceinline__ void rot_cs(float app, float aqq, float apq,
                                       float& c, float& s) {
  float dd = 0.5f * (app - aqq);
  float q2 = apq * apq;
  float hh = dd * dd + q2 + 1e-30f;
  float h = sqrtf(hh);
  float u = fabsf(dd) + h;
  float gi = rsqrtf(u * u + q2);
  c = u * gi;
  float smag = apq * gi;
  s = (dd >= 0.f) ? -smag : smag;
}

// One Jacobi round, static slot pairing (2k,2k+1), data permuted by permf.
// A in LDS chunk-major: SA4g[t*N + j] = rows 4t..4t+3 of column-slot j.
// U rows ping-pong through register arrays ua -> ub (static indices only).
// Partner-column row-phased values come via DPP, not LDS.
template <int N>
__device__ __forceinline__ void jround(float* SAf, float4* SA4g, float2* CSg,
                                       const float* ua, float* ub, int sub,
                                       int kpair, bool isP, int appAddr,
                                       int aqqAddr, int wcol) {
  constexpr int C = N / 4;
  float2 a01 = *(const float2*)(SAf + appAddr);  // app, apq (adjacent rows)
  float aqq = SAf[aqqAddr];
  float c, s;
  rot_cs(a01.x, aqq, a01.y, c, s);
  if (isP) CSg[kpair] = make_float2(c, s);
  float beta = isP ? -s : s;
  wsync();
  const float4* CS4 = (const float4*)CSg;
  float nn[N];
#pragma unroll
  for (int t = 0; t < C; ++t) {
    float4 cs = CS4[t];            // (c,s) of pairs 2t, 2t+1 (broadcast)
    float4 oc = SA4g[t * N + sub]; // own column, rows 4t..4t+3
    {  // pair 2t: rows p=4t, q=4t+1
      const int p = 4 * t, q = 4 * t + 1;
      float xr = cs.x * oc.x - cs.y * oc.y;
      float yr = cs.y * oc.x + cs.x * oc.y;
      float xp = dpp_swap1(xr);
      float yp = dpp_swap1(yr);
      nn[permf(p, N)] = c * xr + beta * xp;
      nn[permf(q, N)] = c * yr + beta * yp;
      float ux = ua[p], uy = ua[q];
      ub[permf(p, N)] = cs.x * ux - cs.y * uy;
      ub[permf(q, N)] = cs.y * ux + cs.x * uy;
    }
    {  // pair 2t+1: rows p=4t+2, q=4t+3
      const int p = 4 * t + 2, q = 4 * t + 3;
      float xr = cs.z * oc.z - cs.w * oc.w;
      float yr = cs.w * oc.z + cs.z * oc.w;
      float xp = dpp_swap1(xr);
      float yp = dpp_swap1(yr);
      nn[permf(p, N)] = c * xr + beta * xp;
      nn[permf(q, N)] = c * yr + beta * yp;
      float ux = ua[p], uy = ua[q];
      ub[permf(p, N)] = cs.z * ux - cs.w * uy;
      ub[permf(q, N)] = cs.w * ux + cs.z * uy;
    }
  }
  wsync();  // all reads of old columns precede any overwrite (lockstep)
#pragma unroll
  for (int t = 0; t < C; ++t)
    SA4g[t * N + wcol] =
        make_float4(nn[4 * t], nn[4 * t + 1], nn[4 * t + 2], nn[4 * t + 3]);
  wsync();
}

// iters must be even (ping-pong); final U rows end in ur.
template <int N>
__device__ __forceinline__ void jacobi_rr(float4* SA4g, float2* CSg, float* ur,
                                          float* un, int sub, int iters) {
  float* SAf = (float*)SA4g;
  const int kpair = sub >> 1;
  const bool isP = !(sub & 1);
  const int pp = sub & ~1;
  const int qq = pp + 1;
  const int appAddr = ((pp >> 2) * N + pp) * 4 + (pp & 3);
  const int aqqAddr = ((qq >> 2) * N + qq) * 4 + (qq & 3);
  const int wcol = permf(sub, N);
#pragma unroll 1
  for (int it = 0; it < iters; it += 2) {
    jround<N>(SAf, SA4g, CSg, ur, un, sub, kpair, isP, appAddr, aqqAddr, wcol);
    jround<N>(SAf, SA4g, CSg, un, ur, sub, kpair, isP, appAddr, aqqAddr, wcol);
  }
}

// Stage 1: X1 = w1^T X w1 (19 padded to 20), ReEig via Jacobi, then
// X2 = Y^T Lam Y with Y = U^T w2. 3 matrices per wave (lanes 60..63 idle ->
// shared dummy slot 6), 128-thread blocks = 6 matrices.
__global__ __launch_bounds__(128, 4) void spd_stage1(
    const float* __restrict__ x, const float* __restrict__ w1,
    const float* __restrict__ w2) {
  __shared__ float4 SA[7 * 100];  // 6 real groups + 1 dummy, 5 chunks x 20
  __shared__ float2 CS[7 * 10];
  __shared__ float SL[7 * 20];
  int tid = threadIdx.x;
  int wid = tid >> 6;
  int lane = tid & 63;
  int gl = lane / 20;  // 0..3 (3 = idle lanes 60..63)
  int sub = lane - gl * 20;
  bool lane_ok = (gl < 3);
  int g = lane_ok ? (wid * 3 + gl) : 6;
  int b = blockIdx.x * 6 + g;
  bool valid = lane_ok && (b < NB);
  int bm = valid ? b : 0;
  float4* SA4g = SA + g * 100;
  float* SAf = (float*)SA4g;
  float2* CSg = CS + g * 10;
  float* SLg = SL + g * 20;

  // ---- bilinear: Z = w1^T X (col sub), then X1 = Z w1 ----
  const float* xb = x + bm * 361;
  float cx[19];
#pragma unroll
  for (int i = 0; i < 19; ++i) cx[i] = (sub < 19) ? xb[i * 19 + sub] : 0.f;
  float z[20];
  z[19] = 0.f;
#pragma unroll
  for (int i = 0; i < 19; ++i) {
    float acc = 0.f;
#pragma unroll
    for (int r = 0; r < 19; ++r) acc += w1[r * 19 + i] * cx[r];
    z[i] = acc;
  }
#pragma unroll
  for (int t = 0; t < 5; ++t)
    SA4g[t * 20 + sub] =
        make_float4(z[4 * t], z[4 * t + 1], z[4 * t + 2], z[4 * t + 3]);
  wsync();
  float wj[19];
#pragma unroll
  for (int r = 0; r < 19; ++r) wj[r] = (sub < 19) ? w1[r * 19 + sub] : 0.f;
  float a1[20];
#pragma unroll
  for (int i = 0; i < 20; ++i) a1[i] = 0.f;
#pragma unroll
  for (int r = 0; r < 19; ++r) {
    float wr = wj[r];
#pragma unroll
    for (int t = 0; t < 5; ++t) {
      float4 zc = SA4g[t * 20 + r];  // Z rows 4t..4t+3, col r (broadcast)
      a1[4 * t + 0] += zc.x * wr;
      a1[4 * t + 1] += zc.y * wr;
      a1[4 * t + 2] += zc.z * wr;
      a1[4 * t + 3] += zc.w * wr;
    }
  }
  wsync();
  // padded A: col 19 = 0 (diag 0 -> clamped to eps; exact invariant subspace)
#pragma unroll
  for (int t = 0; t < 5; ++t)
    SA4g[t * 20 + sub] =
        make_float4(a1[4 * t], a1[4 * t + 1], a1[4 * t + 2], a1[4 * t + 3]);
  float ur[20], un[20];
#pragma unroll
  for (int i = 0; i < 20; ++i) ur[i] = (i == sub) ? 1.f : 0.f;
  wsync();

  jacobi_rr<20>(SA4g, CSg, ur, un, sub, 96);  // 5 sweeps + 1 round, even

  const int dAddr = ((sub >> 2) * 20 + sub) * 4 + (sub & 3);
  float lam = fmaxf(SAf[dAddr], EPS_REC);
  SLg[sub] = lam;
  wsync();
  // SA col sub <- U row sub  (=> SAf elem(i,j) = U[j][i])
#pragma unroll
  for (int t = 0; t < 5; ++t)
    SA4g[t * 20 + sub] =
        make_float4(ur[4 * t], ur[4 * t + 1], ur[4 * t + 2], ur[4 * t + 3]);
  wsync();
  // Y[r][sub] = sum_{i<19} U[i][r] * w2[i][sub]
  float wj2[19];
#pragma unroll
  for (int i = 0; i < 19; ++i) wj2[i] = (sub < 16) ? w2[i * 16 + sub] : 0.f;
  float y[20];
#pragma unroll
  for (int r = 0; r < 20; ++r) y[r] = 0.f;
#pragma unroll
  for (int i = 0; i < 19; ++i) {
    float wv = wj2[i];
#pragma unroll
    for (int t = 0; t < 5; ++t) {
      float4 u4 = SA4g[t * 20 + i];  // U[i][4t..4t+3] (broadcast)
      y[4 * t + 0] += u4.x * wv;
      y[4 * t + 1] += u4.y * wv;
      y[4 * t + 2] += u4.z * wv;
      y[4 * t + 3] += u4.w * wv;
    }
  }
  wsync();
#pragma unroll
  for (int t = 0; t < 5; ++t)
    SA4g[t * 20 + sub] =
        make_float4(y[4 * t], y[4 * t + 1], y[4 * t + 2], y[4 * t + 3]);
  wsync();
  float tr[20];
#pragma unroll
  for (int r = 0; r < 20; ++r) tr[r] = SLg[r] * y[r];
  if (valid && sub < 16) {
    float* outb = g_x2 + b * 256;
#pragma unroll
    for (int i = 0; i < 16; ++i) {
      float acc = 0.f;
#pragma unroll
      for (int t = 0; t < 5; ++t) {
        float4 yc = SA4g[t * 20 + i];  // Y rows 4t..4t+3, col i (broadcast)
        acc += yc.x * tr[4 * t] + yc.y * tr[4 * t + 1] + yc.z * tr[4 * t + 2] +
               yc.w * tr[4 * t + 3];
      }
      outb[i * 16 + sub] = acc;
    }
  }
}

// Stage 2: ReEig(16) via Jacobi, X3 = Y3^T Lam Y3 with Y3 = U^T w3 (16x4).
// 4 matrices per wave, 128-thread blocks = 8 matrices, all lanes active.
__global__ __launch_bounds__(128, 4) void spd_stage2(
    const float* __restrict__ w3) {
  __shared__ float4 SA[8 * 64];
  __shared__ float2 CS[8 * 8];
  __shared__ float SL[8 * 16];
  __shared__ float4 YL[8 * 16];
  int tid = threadIdx.x;
  int wid = tid >> 6;
  int lane = tid & 63;
  int gl = lane >> 4;
  int sub = lane & 15;
  int g = wid * 4 + gl;
  int b = blockIdx.x * 8 + g;
  float4* SA4g = SA + g * 64;
  float* SAf = (float*)SA4g;
  float2* CSg = CS + g * 8;
  float* SLg = SL + g * 16;
  float* YLf = (float*)(YL + g * 16);

  const float* xb = g_x2 + b * 256;
  float ca[16];
#pragma unroll
  for (int i = 0; i < 16; ++i) ca[i] = xb[i * 16 + sub];
#pragma unroll
  for (int t = 0; t < 4; ++t)
    SA4g[t * 16 + sub] =
        make_float4(ca[4 * t], ca[4 * t + 1], ca[4 * t + 2], ca[4 * t + 3]);
  float ur[16], un[16];
#pragma unroll
  for (int i = 0; i < 16; ++i) ur[i] = (i == sub) ? 1.f : 0.f;
  wsync();

  jacobi_rr<16>(SA4g, CSg, ur, un, sub, 76);  // 5 sweeps + 1 round, even

  const int dAddr = ((sub >> 2) * 16 + sub) * 4 + (sub & 3);
  float lam = fmaxf(SAf[dAddr], EPS_REC);
  SLg[sub] = lam;
  wsync();
#pragma unroll
  for (int t = 0; t < 4; ++t)
    SA4g[t * 16 + sub] =
        make_float4(ur[4 * t], ur[4 * t + 1], ur[4 * t + 2], ur[4 * t + 3]);
  wsync();
  // Y3[sub][j] = sum_i U[i][sub]*w3[i][j]; U[i][sub] = SAf elem(sub,i)
  float y3[4] = {0.f, 0.f, 0.f, 0.f};
  const int rowBase = (sub >> 2) * 64 + (sub & 3);
#pragma unroll
  for (int i = 0; i < 16; ++i) {
    float u = SAf[rowBase + i * 4];
#pragma unroll
    for (int j = 0; j < 4; ++j) y3[j] += u * w3[i * 4 + j];
  }
  ((float4*)YLf)[sub] = make_float4(y3[0], y3[1], y3[2], y3[3]);
  wsync();
  int ii = sub >> 2, jj = sub & 3;
  float acc = 0.f;
#pragma unroll
  for (int r = 0; r < 16; ++r)
    acc += SLg[r] * YLf[r * 4 + ii] * YLf[r * 4 + jj];
  g_x3[b * 16 + sub] = acc;
}

// Stage 3: per-thread 4x4 LogEig in registers, FC(16->2), log_softmax.
__global__ __launch_bounds__(256) void spd_stage3(const float* __restrict__ fcw,
                                                  float* __restrict__ out) {
  int b = blockIdx.x * 256 + threadIdx.x;
  const float* xb = g_x3 + b * 16;
  float a[4][4];
#pragma unroll
  for (int i = 0; i < 4; ++i)
#pragma unroll
    for (int j = 0; j < 4; ++j) a[i][j] = xb[i * 4 + j];
  float vv[4][4];
#pragma unroll
  for (int i = 0; i < 4; ++i)
#pragma unroll
    for (int j = 0; j < 4; ++j) vv[i][j] = (i == j) ? 1.f : 0.f;

  constexpr int P4[6] = {0, 0, 0, 1, 1, 2};
  constexpr int Q4[6] = {1, 2, 3, 2, 3, 3};
  for (int sw = 0; sw < 6; ++sw) {
#pragma unroll
    for (int e = 0; e < 6; ++e) {
      const int p = P4[e], q = Q4[e];
      float c, s;
      rot_cs(a[p][p], a[q][q], a[p][q], c, s);
#pragma unroll
      for (int j = 0; j < 4; ++j) {
        float xx = a[p][j], yy = a[q][j];
        a[p][j] = c * xx - s * yy;
        a[q][j] = s * xx + c * yy;
      }
#pragma unroll
      for (int i = 0; i < 4; ++i) {
        float xx = a[i][p], yy = a[i][q];
        a[i][p] = c * xx - s * yy;
        a[i][q] = s * xx + c * yy;
      }
#pragma unroll
      for (int i = 0; i < 4; ++i) {
        float xx = vv[i][p], yy = vv[i][q];
        vv[i][p] = c * xx - s * yy;
        vv[i][q] = s * xx + c * yy;
      }
    }
  }
  float ll[4];
#pragma unroll
  for (int r = 0; r < 4; ++r) ll[r] = logf(fmaxf(a[r][r], 1e-12f));
  float feat[16];
#pragma unroll
  for (int i = 0; i < 4; ++i)
#pragma unroll
    for (int j = 0; j < 4; ++j) {
      float acc = 0.f;
#pragma unroll
      for (int r = 0; r < 4; ++r) acc += ll[r] * vv[i][r] * vv[j][r];
      feat[i * 4 + j] = acc;
    }
  float z0 = 0.f, z1 = 0.f;
#pragma unroll
  for (int k = 0; k < 16; ++k) {
    z0 += feat[k] * fcw[2 * k + 0];
    z1 += feat[k] * fcw[2 * k + 1];
  }
  float m = fmaxf(z0, z1);
  float lse = logf(expf(z0 - m) + expf(z1 - m));
  out[b * 2 + 0] = z0 - m - lse;
  out[b * 2 + 1] = z1 - m - lse;
#pragma unroll
  for (int k = 0; k < 16; ++k) out[2 * NB + b * 16 + k] = feat[k];
}

extern "C" void kernel_launch(void* const* d_in, const int* in_sizes, int n_in,
                              void* d_out, int out_size, void* d_ws,
                              size_t ws_size, hipStream_t stream) {
  (void)in_sizes;
  (void)n_in;
  (void)out_size;
  (void)d_ws;
  (void)ws_size;
  const float* x = (const float*)d_in[0];
  const float* w1 = (const float*)d_in[1];
  const float* w2 = (const float*)d_in[2];
  const float* w3 = (const float*)d_in[3];
  const float* fcw = (const float*)d_in[4];
  float* out = (float*)d_out;

  spd_stage1<<<(NB + 5) / 6, 128, 0, stream>>>(x, w1, w2);
  spd_stage2<<<NB / 8, 128, 0, stream>>>(w3);
  spd_stage3<<<NB / 256, 256, 0, stream>>>(fcw, out);
}